// Round 11
// baseline (548.064 us; speedup 1.0000x reference)
//
#include <hip/hip_runtime.h>
#include <hip/hip_fp16.h>

#define NNODES 100000
#define NEDGES 1600000
#define BN_EPS 1e-5f
#define L2_EPS 1e-12f

#define BKT_SHIFT 6
#define BKT_SIZE  64             // bucket == layer tile (64 nodes)
#define NBKT      1563           // ceil(100000/64)
#define CHUNK     16384
#define NBLK_E    98             // ceil(1600000/16384)
#define NSLOT     64             // BN-stats shard count
#define SRCMASK   0x03FFFFFFu    // low 26 bits of packed edge = src id

// ---------------------------------------------------------------------------
// Wave-level block exclusive scan (NT threads). Leading barrier protects wsum
// reuse across consecutive calls.
template<int NT>
__device__ __forceinline__ int block_excl_scan(int v, int* wsum) {
    __syncthreads();
    constexpr int NW = NT / 64;
    int incl = v;
#pragma unroll
    for (int off = 1; off < 64; off <<= 1) {
        int t = __shfl_up(incl, off);
        if ((threadIdx.x & 63) >= off) incl += t;
    }
    int wid = threadIdx.x >> 6;
    if ((threadIdx.x & 63) == 63) wsum[wid] = incl;
    __syncthreads();
    if (threadIdx.x < NW) {
        int w = wsum[threadIdx.x];
#pragma unroll
        for (int off = 1; off < NW; off <<= 1) {
            int t = __shfl_up(w, off);
            if ((int)threadIdx.x >= off) w += t;
        }
        wsum[threadIdx.x] = w;             // inclusive wave sums
    }
    __syncthreads();
    int base = wid ? wsum[wid - 1] : 0;
    return base + incl - v;
}

// ---------------------------------------------------------------------------
// Pass 1: per-chunk bucket histogram (LDS, 1563 buckets) -> transposed
// blk_hist. Block 0 also zeroes the sharded BN stats accumulators.
__global__ void hist_kernel(const int* __restrict__ dst,
                            int* __restrict__ blk_hist_T, float* __restrict__ stats) {
    __shared__ int h[NBKT];
    for (int i = threadIdx.x; i < NBKT; i += blockDim.x) h[i] = 0;
    if (blockIdx.x == 0)
        for (int i = threadIdx.x; i < 3 * NSLOT * 64; i += blockDim.x) stats[i] = 0.0f;
    __syncthreads();
    int base = blockIdx.x * CHUNK;
    int end  = min(base + CHUNK, NEDGES);
    for (int e = base + threadIdx.x * 4; e < end; e += blockDim.x * 4) {
        int4 d = *reinterpret_cast<const int4*>(dst + e);
        atomicAdd(&h[d.x >> BKT_SHIFT], 1);
        atomicAdd(&h[d.y >> BKT_SHIFT], 1);
        atomicAdd(&h[d.z >> BKT_SHIFT], 1);
        atomicAdd(&h[d.w >> BKT_SHIFT], 1);
    }
    __syncthreads();
    for (int i = threadIdx.x; i < NBKT; i += blockDim.x)
        blk_hist_T[i * NBLK_E + blockIdx.x] = h[i];   // [bucket][chunk]
}

// Per-bucket exclusive scan across chunks + bucket totals as by-product.
__global__ void scan_blocks(const int* __restrict__ blk_hist_T,
                            int* __restrict__ blk_off, int* __restrict__ bucket_total) {
    __shared__ int wsum[4];
    int b = blockIdx.x;
    int i = threadIdx.x;
    int v = (i < NBLK_E) ? blk_hist_T[b * NBLK_E + i] : 0;
    int excl = block_excl_scan<256>(v, wsum);
    if (i < NBLK_E) blk_off[i * NBKT + b] = excl;     // [chunk][bucket]
    if (i == 255) bucket_total[b] = excl + v;
}

// Exclusive scan of 1563 bucket totals -> bucket_base[NBKT+1]. 1 block,
// 4 items/thread.
__global__ void scan_buckets(const int* __restrict__ bucket_total,
                             int* __restrict__ bucket_base) {
    __shared__ int wsum[8];
    int t = threadIdx.x;
    int base4 = t * 4;
    int v[4]; int s = 0;
#pragma unroll
    for (int k = 0; k < 4; k++) {
        v[k] = (base4 + k < NBKT) ? bucket_total[base4 + k] : 0;
        s += v[k];
    }
    int excl = block_excl_scan<512>(s, wsum);
    int run = excl;
#pragma unroll
    for (int k = 0; k < 4; k++) {
        if (base4 + k < NBKT) bucket_base[base4 + k] = run;
        run += v[k];
    }
    if (t == 0) bucket_base[NBKT] = NEDGES;
}

// Pass 2: scatter edges into bucket segments: staged = dst_local(6b)<<26|src.
// No within-bucket sort needed (layers aggregate edge-parallel).
__global__ void bucket_scatter(const int* __restrict__ src, const int* __restrict__ dst,
                               const int* __restrict__ blk_off, const int* __restrict__ bucket_base,
                               unsigned int* __restrict__ staged) {
    __shared__ int cur[NBKT];
    for (int i = threadIdx.x; i < NBKT; i += blockDim.x)
        cur[i] = bucket_base[i] + blk_off[blockIdx.x * NBKT + i];
    __syncthreads();
    int base = blockIdx.x * CHUNK;
    int end  = min(base + CHUNK, NEDGES);
    for (int e = base + threadIdx.x * 4; e < end; e += blockDim.x * 4) {
        int4 d = *reinterpret_cast<const int4*>(dst + e);
        int4 s = *reinterpret_cast<const int4*>(src + e);
        int p0 = atomicAdd(&cur[d.x >> BKT_SHIFT], 1);
        staged[p0] = ((unsigned)(d.x & (BKT_SIZE - 1)) << 26) | (unsigned)s.x;
        int p1 = atomicAdd(&cur[d.y >> BKT_SHIFT], 1);
        staged[p1] = ((unsigned)(d.y & (BKT_SIZE - 1)) << 26) | (unsigned)s.y;
        int p2 = atomicAdd(&cur[d.z >> BKT_SHIFT], 1);
        staged[p2] = ((unsigned)(d.z & (BKT_SIZE - 1)) << 26) | (unsigned)s.z;
        int p3 = atomicAdd(&cur[d.w >> BKT_SHIFT], 1);
        staged[p3] = ((unsigned)(d.w & (BKT_SIZE - 1)) << 26) | (unsigned)s.w;
    }
}

// ---------------------------------------------------------------------------
__device__ __forceinline__ void unpack8(uint4 v, float* f) {
    float2 a = __half22float2(*(const __half2*)&v.x);
    float2 b = __half22float2(*(const __half2*)&v.y);
    float2 c = __half22float2(*(const __half2*)&v.z);
    float2 d = __half22float2(*(const __half2*)&v.w);
    f[0] = a.x; f[1] = a.y; f[2] = b.x; f[3] = b.y;
    f[4] = c.x; f[5] = c.y; f[6] = d.x; f[7] = d.y;
}

// Row load for Phase B: fp16 rows as 1-2 uint4, fp32 rows as float4s.
template<int CI, int SI, bool H>
__device__ __forceinline__ void load_row2(const void* base, long node, float* r) {
    if constexpr (H) {
        const __half* p = (const __half*)base + node * SI;
        float t[SI > 8 ? 16 : 8];
        uint4 v0 = *(const uint4*)p;
        unpack8(v0, t);
        if constexpr (SI > 8) {
            uint4 v1 = *(const uint4*)(p + 8);
            unpack8(v1, t + 8);
        }
#pragma unroll
        for (int c = 0; c < CI; c++) r[c] = t[c];
    } else {
        const float* p = (const float*)base + node * SI;
#pragma unroll
        for (int c = 0; c < CI; c += 4) {
            float4 v = *(const float4*)(p + c);
            r[c] = v.x; r[c+1] = v.y; r[c+2] = v.z; r[c+3] = v.w;
        }
    }
}

// ---------------------------------------------------------------------------
// Bucket-parallel fused layer. Block = 64-node bucket; its edges are the
// contiguous staged[beg..end) segment (arbitrary dst order -> LDS atomics
// land on RANDOM addresses; round-4's same-address serialization cannot
// occur). Phase A: thread = (edge slot, 16B chunk); 2-deep prefetch; deg
// counted in-pass. Phase B: 8 thr/node linear + L2 norm + ReLU + BN stats.
// No CSR, no row_ptr, no butterfly. fp16 tables (round-10 proven), fp32 math.
template<int CI, int CIL, int SI, int CO, int SO,
         bool IN_HALF, bool OUT_HALF, bool IN_AFFINE, bool DO_STATS>
__global__ __launch_bounds__(512, 4)
void layer_kernel(const unsigned* __restrict__ staged, const int* __restrict__ bucket_base,
                  const void* __restrict__ h,
                  const float* __restrict__ ssum_in, const float* __restrict__ ssq_in,
                  const float* __restrict__ g_in, const float* __restrict__ b_in,
                  const float* __restrict__ wl, const float* __restrict__ bl,
                  const float* __restrict__ wr,
                  void* __restrict__ y,
                  float* __restrict__ stat_sum, float* __restrict__ stat_sq) {
    constexpr int W    = IN_HALF ? 8 : 4;    // channels per 16B chunk
    constexpr int CIp  = CI + 1;
    constexpr int CILp = CIL + 1;            // padded acc stride
    constexpr int NCH  = CIL / W;            // chunks per edge (1 or 2)
    constexpr int EPI  = 512 / NCH;          // edge slots per iteration
    constexpr int TPN  = 8;                  // threads per node in Phase B
    constexpr int OPT  = (CO + TPN - 1) / TPN;

    __shared__ float acc[BKT_SIZE * CILp];
    __shared__ int   deg[BKT_SIZE];
    __shared__ float sWl[CO * CIp];
    __shared__ float sWr[CO * CIp];
    __shared__ float sBl[CO];
    __shared__ float sSc[CI];
    __shared__ float sSh[CI];
    __shared__ float sSumR[CI];
    __shared__ float sSqR[CI];
    __shared__ float red_sum[CO];
    __shared__ float red_sq[CO];

    int tid = threadIdx.x;
    int b   = blockIdx.x;

    for (int i = tid; i < CO * CI; i += 512) {
        int o = i / CI, c = i - o * CI;
        sWl[o * CIp + c] = wl[i];
        sWr[o * CIp + c] = wr[i];
    }
    if (tid < CO) {
        sBl[tid] = bl[tid];
        if (DO_STATS) { red_sum[tid] = 0.0f; red_sq[tid] = 0.0f; }
    }
    for (int i = tid; i < BKT_SIZE * CILp; i += 512) acc[i] = 0.0f;
    if (tid < BKT_SIZE) deg[tid] = 0;
    if (IN_AFFINE && tid < CI) { sSumR[tid] = 0.0f; sSqR[tid] = 0.0f; }
    __syncthreads();
    if (IN_AFFINE) {
        int c = tid & 31, sl = tid >> 5;     // 16 slices over NSLOT shards
        if (c < CI) {
            float ps = 0.0f, pq = 0.0f;
#pragma unroll
            for (int s = sl; s < NSLOT; s += 16) {
                ps += ssum_in[s * 64 + c];
                pq += ssq_in[s * 64 + c];
            }
            atomicAdd(&sSumR[c], ps);
            atomicAdd(&sSqR[c], pq);
        }
        __syncthreads();
        if (tid < CI) {
            float m  = sSumR[tid] * (1.0f / NNODES);
            float vv = sSqR[tid] * (1.0f / NNODES) - m * m;
            float s  = g_in[tid] / sqrtf(vv + BN_EPS);
            sSc[tid] = s;
            sSh[tid] = b_in[tid] - m * s;
        }
        __syncthreads();
    }

    // ---- Phase A: edge-parallel LDS-atomic accumulate (random dst order) ----
    {
        int beg = bucket_base[b], end = bucket_base[b + 1];
        int slot = tid / NCH;
        int ch   = (tid & (NCH - 1)) * W;

        auto ldrow = [&](unsigned pk) -> uint4 {
            long src = (long)(pk & SRCMASK);
            if constexpr (IN_HALF) {
                return *(const uint4*)((const __half*)h + src * SI + ch);
            } else {
                float4 f = *(const float4*)((const float*)h + src * SI + ch);
                return *(uint4*)&f;
            }
        };

        int e = beg + slot;
        unsigned pk0 = (e < end) ? staged[e] : 0u;
        unsigned pk1 = (e + EPI < end) ? staged[e + EPI] : 0u;
        uint4 r0 = (e < end) ? ldrow(pk0) : make_uint4(0, 0, 0, 0);

        for (; e < end; e += EPI) {
            unsigned pk2 = (e + 2 * EPI < end) ? staged[e + 2 * EPI] : 0u;
            uint4 r1 = (e + EPI < end) ? ldrow(pk1) : make_uint4(0, 0, 0, 0);

            int dl = (int)(pk0 >> 26);
            float f[W];
            if constexpr (IN_HALF) unpack8(r0, f);
            else { float4 t = *(float4*)&r0; f[0] = t.x; f[1] = t.y; f[2] = t.z; f[3] = t.w; }
            int a = dl * CILp + ch;
#pragma unroll
            for (int q = 0; q < W; q++) atomicAdd(&acc[a + q], f[q]);
            if (NCH == 1 || (tid & (NCH - 1)) == 0) atomicAdd(&deg[dl], 1);

            pk0 = pk1; pk1 = pk2; r0 = r1;
        }
    }
    __syncthreads();

    // ---- Phase B: node-parallel epilogue (8 threads per node) ----
    {
        int nl = tid >> 3, t = tid & 7;
        int node = b * BKT_SIZE + nl;
        bool valid = node < NNODES;

        float outv[OPT];
        float nrm2 = 0.0f;
        if (valid) {
            float ic = 1.0f / fmaxf((float)deg[nl], 1.0f);
            float a[CI], xin[CI];
            load_row2<CI, SI, IN_HALF>(h, node, xin);
#pragma unroll
            for (int c = 0; c < CI; c++) {
                float av = acc[nl * CILp + c] * ic;
                float xv = xin[c];
                if (IN_AFFINE) {
                    av = av * sSc[c] + sSh[c];
                    xv = xv * sSc[c] + sSh[c];
                }
                a[c] = av;
                xin[c] = xv;
            }
#pragma unroll
            for (int k = 0; k < OPT; k++) {
                int o = t * OPT + k;
                float v = 0.0f;
                if (o < CO) {
                    v = sBl[o];
#pragma unroll
                    for (int c = 0; c < CI; c++)
                        v += sWl[o * CIp + c] * a[c] + sWr[o * CIp + c] * xin[c];
                }
                outv[k] = v;
                nrm2 += v * v;
            }
        }
        nrm2 += __shfl_xor(nrm2, 1);         // 8-lane group = one node
        nrm2 += __shfl_xor(nrm2, 2);
        nrm2 += __shfl_xor(nrm2, 4);

        if (valid) {
            float inv_nrm = 1.0f / fmaxf(sqrtf(nrm2), L2_EPS);
#pragma unroll
            for (int k = 0; k < OPT; k++) {
                int o = t * OPT + k;
                float v = (o < CO) ? fmaxf(outv[k] * inv_nrm, 0.0f) : 0.0f;
                if constexpr (OUT_HALF) {
                    if (o < SO) ((__half*)y)[(long)node * SO + o] = __float2half_rn(v);
                } else {
                    if (o < CO) ((float*)y)[(long)node * SO + o] = v;
                }
                if (DO_STATS && o < CO) {
                    atomicAdd(&red_sum[o], v);
                    atomicAdd(&red_sq[o], v * v);
                }
            }
        }
    }

    if (DO_STATS) {
        __syncthreads();
        if (tid < CO) {
            int slot = b & (NSLOT - 1);
            atomicAdd(&stat_sum[slot * 64 + tid], red_sum[tid]);
            atomicAdd(&stat_sq [slot * 64 + tid], red_sq[tid]);
        }
    }
}

// ---------------------------------------------------------------------------
extern "C" void kernel_launch(void* const* d_in, const int* in_sizes, int n_in,
                              void* d_out, int out_size, void* d_ws, size_t ws_size,
                              hipStream_t stream) {
    const float* x   = (const float*)d_in[0];
    const int*   ei  = (const int*)d_in[1];
    const int*   src = ei;
    const int*   dst = ei + NEDGES;

    const float* w1l = (const float*)d_in[2];
    const float* b1l = (const float*)d_in[3];
    const float* w1r = (const float*)d_in[4];
    const float* w2l = (const float*)d_in[5];
    const float* b2l = (const float*)d_in[6];
    const float* w2r = (const float*)d_in[7];
    const float* w3l = (const float*)d_in[8];
    const float* b3l = (const float*)d_in[9];
    const float* w3r = (const float*)d_in[10];
    const float* w4l = (const float*)d_in[11];
    const float* b4l = (const float*)d_in[12];
    const float* w4r = (const float*)d_in[13];
    const float* g1  = (const float*)d_in[14];
    const float* be1 = (const float*)d_in[15];
    const float* g2  = (const float*)d_in[16];
    const float* be2 = (const float*)d_in[17];
    const float* g3  = (const float*)d_in[18];
    const float* be3 = (const float*)d_in[19];

    char* w = (char*)d_ws;
    int* blk_hist     = (int*)w;  w += NBKT * NBLK_E * 4;
    int* blk_off      = (int*)w;  w += NBLK_E * NBKT * 4;
    int* bucket_total = (int*)w;  w += ((NBKT + 15) & ~15) * 4;
    int* bucket_base  = (int*)w;  w += ((NBKT + 16) & ~15) * 4;
    unsigned int* staged = (unsigned int*)w; w += NEDGES * 4;
    __half* hA        = (__half*)w; w += NNODES * 16 * 4;  // fp16 tables (slab)
    __half* hB        = (__half*)w; w += NNODES * 16 * 4;
    float* stats      = (float*)w; w += 3 * NSLOT * 64 * 4;

    float* ssum1 = stats + 0 * NSLOT * 64, *ssq1 = ssum1 + 32;
    float* ssum2 = stats + 1 * NSLOT * 64, *ssq2 = ssum2 + 32;
    float* ssum3 = stats + 2 * NSLOT * 64, *ssq3 = ssum3 + 32;

    // bucket build (no within-bucket sort; CSR eliminated)
    hist_kernel   <<<NBLK_E, 512, 0, stream>>>(dst, blk_hist, stats);
    scan_blocks   <<<NBKT, 256, 0, stream>>>(blk_hist, blk_off, bucket_total);
    scan_buckets  <<<1, 512, 0, stream>>>(bucket_total, bucket_base);
    bucket_scatter<<<NBLK_E, 512, 0, stream>>>(src, dst, blk_off, bucket_base, staged);

    // layer 1: 4 -> 6; in fp32 x (SI=4), out fp16 hA (SO=8 halves), +stats
    layer_kernel<4, 4, 4, 6, 8, false, true, false, true><<<NBKT, 512, 0, stream>>>(
        staged, bucket_base, x, nullptr, nullptr, nullptr, nullptr,
        w1l, b1l, w1r, hA, ssum1, ssq1);

    // layer 2: 6 -> 8; in fp16 hA (CIL=8, pad ch zero), BN1 in-block, out fp16 hB, +stats
    layer_kernel<6, 8, 8, 8, 8, true, true, true, true><<<NBKT, 512, 0, stream>>>(
        staged, bucket_base, hA, ssum1, ssq1, g1, be1,
        w2l, b2l, w2r, hB, ssum2, ssq2);

    // layer 3: 8 -> 16; in fp16 hB (SI=8), BN2, out fp16 hA, +stats
    layer_kernel<8, 8, 8, 16, 16, true, true, true, true><<<NBKT, 512, 0, stream>>>(
        staged, bucket_base, hB, ssum2, ssq2, g2, be2,
        w3l, b3l, w3r, hA, ssum3, ssq3);

    // layer 4: 16 -> 32; in fp16 hA (SI=16, NCH=2), BN3, ReLU -> fp32 d_out
    layer_kernel<16, 16, 16, 32, 32, true, false, true, false><<<NBKT, 512, 0, stream>>>(
        staged, bucket_base, hA, ssum3, ssq3, g3, be3,
        w4l, b4l, w4r, d_out, nullptr, nullptr);
}

// Round 12
// 239.687 us; speedup vs baseline: 2.2866x; 2.2866x over previous
//
#include <hip/hip_runtime.h>
#include <hip/hip_fp16.h>

#define NNODES 100000
#define NEDGES 1600000
#define BN_EPS 1e-5f
#define L2_EPS 1e-12f

#define BKT_SHIFT 9
#define BKT_SIZE  512
#define NBKT      196            // ceil(100000/512)
#define CHUNK     8192
#define NBLK_E    196            // ceil(1600000/8192)
#define NSLOT     64             // BN-stats shard count

// ---------------------------------------------------------------------------
// Wave-level block exclusive scan (NT threads). Leading barrier protects wsum
// reuse across consecutive calls.
template<int NT>
__device__ __forceinline__ int block_excl_scan(int v, int* wsum) {
    __syncthreads();
    constexpr int NW = NT / 64;
    int incl = v;
#pragma unroll
    for (int off = 1; off < 64; off <<= 1) {
        int t = __shfl_up(incl, off);
        if ((threadIdx.x & 63) >= off) incl += t;
    }
    int wid = threadIdx.x >> 6;
    if ((threadIdx.x & 63) == 63) wsum[wid] = incl;
    __syncthreads();
    if (threadIdx.x < NW) {
        int w = wsum[threadIdx.x];
#pragma unroll
        for (int off = 1; off < NW; off <<= 1) {
            int t = __shfl_up(w, off);
            if ((int)threadIdx.x >= off) w += t;
        }
        wsum[threadIdx.x] = w;             // inclusive wave sums
    }
    __syncthreads();
    int base = wid ? wsum[wid - 1] : 0;
    return base + incl - v;
}

// ---------------------------------------------------------------------------
// Pass 1: per-block bucket histogram (LDS) -> transposed blk_hist. Block 0
// also zeroes the sharded BN stats accumulators.
__global__ void hist_kernel(const int* __restrict__ dst,
                            int* __restrict__ blk_hist_T, float* __restrict__ stats) {
    __shared__ int h[NBKT];
    for (int i = threadIdx.x; i < NBKT; i += blockDim.x) h[i] = 0;
    if (blockIdx.x == 0)
        for (int i = threadIdx.x; i < 3 * NSLOT * 64; i += blockDim.x) stats[i] = 0.0f;
    __syncthreads();
    int base = blockIdx.x * CHUNK;
    int end  = min(base + CHUNK, NEDGES);
    for (int e = base + threadIdx.x * 4; e < end; e += blockDim.x * 4) {
        int4 d = *reinterpret_cast<const int4*>(dst + e);
        atomicAdd(&h[d.x >> BKT_SHIFT], 1);
        atomicAdd(&h[d.y >> BKT_SHIFT], 1);
        atomicAdd(&h[d.z >> BKT_SHIFT], 1);
        atomicAdd(&h[d.w >> BKT_SHIFT], 1);
    }
    __syncthreads();
    for (int i = threadIdx.x; i < NBKT; i += blockDim.x)
        blk_hist_T[i * NBLK_E + blockIdx.x] = h[i];   // [bucket][block]
}

// Per-bucket exclusive scan across blocks + bucket totals as by-product.
__global__ void scan_blocks(const int* __restrict__ blk_hist_T,
                            int* __restrict__ blk_off, int* __restrict__ bucket_total) {
    __shared__ int wsum[4];
    int b = blockIdx.x;
    int i = threadIdx.x;
    int v = (i < NBLK_E) ? blk_hist_T[b * NBLK_E + i] : 0;
    int excl = block_excl_scan<256>(v, wsum);
    if (i < NBLK_E) blk_off[i * NBKT + b] = excl;     // [block][bucket]
    if (i == 255) bucket_total[b] = excl + v;
}

// Pass 2: scatter edges into bucket segments (packed dst_local<<23 | src).
__global__ void bucket_scatter(const int* __restrict__ src, const int* __restrict__ dst,
                               const int* __restrict__ blk_off, const int* __restrict__ bucket_total,
                               unsigned int* __restrict__ staged) {
    __shared__ int cur[NBKT];
    __shared__ int wsum[8];
    int v = (threadIdx.x < NBKT) ? bucket_total[threadIdx.x] : 0;
    int bbase = block_excl_scan<512>(v, wsum);
    if (threadIdx.x < NBKT)
        cur[threadIdx.x] = bbase + blk_off[blockIdx.x * NBKT + threadIdx.x];
    __syncthreads();
    int base = blockIdx.x * CHUNK;
    int end  = min(base + CHUNK, NEDGES);
    for (int e = base + threadIdx.x * 4; e < end; e += blockDim.x * 4) {
        int4 d = *reinterpret_cast<const int4*>(dst + e);
        int4 s = *reinterpret_cast<const int4*>(src + e);
        int p0 = atomicAdd(&cur[d.x >> BKT_SHIFT], 1);
        staged[p0] = ((unsigned)(d.x & (BKT_SIZE - 1)) << 23) | (unsigned)s.x;
        int p1 = atomicAdd(&cur[d.y >> BKT_SHIFT], 1);
        staged[p1] = ((unsigned)(d.y & (BKT_SIZE - 1)) << 23) | (unsigned)s.y;
        int p2 = atomicAdd(&cur[d.z >> BKT_SHIFT], 1);
        staged[p2] = ((unsigned)(d.z & (BKT_SIZE - 1)) << 23) | (unsigned)s.z;
        int p3 = atomicAdd(&cur[d.w >> BKT_SHIFT], 1);
        staged[p3] = ((unsigned)(d.w & (BKT_SIZE - 1)) << 23) | (unsigned)s.w;
    }
}

// Pass 3: one block per bucket -> exact CSR (row_ptr + node-sorted col).
__global__ void csr_finalize(const unsigned int* __restrict__ staged,
                             const int* __restrict__ bucket_total,
                             int* __restrict__ row_ptr, int* __restrict__ col) {
    __shared__ int nh[BKT_SIZE];
    __shared__ int cur[BKT_SIZE];
    __shared__ int wsum[8];
    __shared__ int sBeg, sEnd;
    int b = blockIdx.x;

    nh[threadIdx.x] = 0;                      // covered by scan's leading barrier
    int v = (threadIdx.x < NBKT) ? bucket_total[threadIdx.x] : 0;
    int excl = block_excl_scan<512>(v, wsum);
    if (threadIdx.x == b) { sBeg = excl; sEnd = excl + v; }
    __syncthreads();
    int beg = sBeg, end = sEnd;

    for (int e = beg + threadIdx.x; e < end; e += blockDim.x)
        atomicAdd(&nh[staged[e] >> 23], 1);
    __syncthreads();

    int hv = nh[threadIdx.x];
    int hexcl = block_excl_scan<512>(hv, wsum);

    int node = b * BKT_SIZE + threadIdx.x;
    if (node < NNODES) row_ptr[node] = beg + hexcl;
    if (b == 0 && threadIdx.x == 0) row_ptr[NNODES] = NEDGES;
    cur[threadIdx.x] = hexcl;
    __syncthreads();

    for (int e = beg + threadIdx.x; e < end; e += blockDim.x) {
        unsigned pk = staged[e];
        int l = (int)(pk >> 23);
        int p = atomicAdd(&cur[l], 1);          // LDS atomic only
        col[beg + p] = (int)(pk & 0x7FFFFF);
    }
}

// ---------------------------------------------------------------------------
__device__ __forceinline__ void unpack8(uint4 v, float* f) {
    float2 a = __half22float2(*(const __half2*)&v.x);
    float2 b = __half22float2(*(const __half2*)&v.y);
    float2 c = __half22float2(*(const __half2*)&v.z);
    float2 d = __half22float2(*(const __half2*)&v.w);
    f[0] = a.x; f[1] = a.y; f[2] = b.x; f[3] = b.y;
    f[4] = c.x; f[5] = c.y; f[6] = d.x; f[7] = d.y;
}

// Row load: fp16 rows as 1-2 uint4 (8 halves each), fp32 rows as float4s.
template<int CI, int SI, bool H>
__device__ __forceinline__ void load_row2(const void* base, long node, float* r) {
    if constexpr (H) {
        const __half* p = (const __half*)base + node * SI;
        float t[SI > 8 ? 16 : 8];
        uint4 v0 = *(const uint4*)p;
        unpack8(v0, t);
        if constexpr (SI > 8) {
            uint4 v1 = *(const uint4*)(p + 8);
            unpack8(v1, t + 8);
        }
#pragma unroll
        for (int c = 0; c < CI; c++) r[c] = t[c];
    } else {
        const float* p = (const float*)base + node * SI;
#pragma unroll
        for (int c = 0; c < CI; c += 4) {
            float4 v = *(const float4*)(p + c);
            r[c] = v.x; r[c+1] = v.y; r[c+2] = v.z; r[c+3] = v.w;
        }
    }
}

// ---------------------------------------------------------------------------
// Lane-group fused layer (round-2 structure, proven): G lanes/node, gather
// pipeline in registers, butterfly reduce, LDS weights padded to CI+1.
// fp16 intermediate tables (L2-resident -> gather latency ~200cy instead of
// LLC ~600cy; half the 16B loads). All math fp32.
template<int CI, int SI, int CO, int SO, int G,
         bool IN_HALF, bool OUT_HALF, bool IN_AFFINE, bool DO_STATS>
__global__ void layer_kernel(const int* __restrict__ row_ptr, const int* __restrict__ col,
                             const void* __restrict__ h,
                             const float* __restrict__ ssum_in, const float* __restrict__ ssq_in,
                             const float* __restrict__ g_in, const float* __restrict__ b_in,
                             const float* __restrict__ wl, const float* __restrict__ bl,
                             const float* __restrict__ wr,
                             void* __restrict__ y,
                             float* __restrict__ stat_sum, float* __restrict__ stat_sq) {
    constexpr int NPB = 256 / G;             // nodes per block
    constexpr int OPL = (CO + G - 1) / G;    // outputs per lane
    constexpr int PCI = CI + 1;              // padded LDS stride

    __shared__ float sWl[CO * PCI];
    __shared__ float sWr[CO * PCI];
    __shared__ float sBl[CO];
    __shared__ float sSc[CI];
    __shared__ float sSh[CI];
    __shared__ float sSumR[CI];
    __shared__ float sSqR[CI];
    __shared__ float red_sum[CO];
    __shared__ float red_sq[CO];

    for (int i = threadIdx.x; i < CO * CI; i += blockDim.x) {
        int o = i / CI, c = i - o * CI;
        sWl[o * PCI + c] = wl[i];
        sWr[o * PCI + c] = wr[i];
    }
    if (threadIdx.x < CO) {
        sBl[threadIdx.x] = bl[threadIdx.x];
        if (DO_STATS) { red_sum[threadIdx.x] = 0.0f; red_sq[threadIdx.x] = 0.0f; }
    }
    if (IN_AFFINE && threadIdx.x < CI) { sSumR[threadIdx.x] = 0.0f; sSqR[threadIdx.x] = 0.0f; }
    __syncthreads();
    if (IN_AFFINE) {
        int c = threadIdx.x & 31, sl = threadIdx.x >> 5;    // 8 slices over NSLOT
        if (c < CI) {
            float ps = 0.0f, pq = 0.0f;
#pragma unroll
            for (int s = sl; s < NSLOT; s += 8) {
                ps += ssum_in[s * 64 + c];
                pq += ssq_in[s * 64 + c];
            }
            atomicAdd(&sSumR[c], ps);
            atomicAdd(&sSqR[c], pq);
        }
        __syncthreads();
        if (threadIdx.x < CI) {
            float m  = sSumR[threadIdx.x] * (1.0f / NNODES);
            float vv = sSqR[threadIdx.x] * (1.0f / NNODES) - m * m;
            float s  = g_in[threadIdx.x] / sqrtf(vv + BN_EPS);
            sSc[threadIdx.x] = s;
            sSh[threadIdx.x] = b_in[threadIdx.x] - m * s;
        }
    }
    __syncthreads();

    int node = blockIdx.x * NPB + (threadIdx.x / G);
    int g    = threadIdx.x & (G - 1);
    bool valid = node < NNODES;

    float acc[CI];
#pragma unroll
    for (int c = 0; c < CI; c++) acc[c] = 0.0f;

    int beg = 0, end = 0;
    if (valid) {
        beg = row_ptr[node];
        end = row_ptr[node + 1];
        int j = beg + g;
        if constexpr (CI <= 8) {
            // 4 rows in flight (register-safe only for small rows)
            for (; j + 3 * G < end; j += 4 * G) {
                int i0 = col[j], i1 = col[j + G], i2 = col[j + 2 * G], i3 = col[j + 3 * G];
                float r0[CI], r1[CI], r2[CI], r3[CI];
                load_row2<CI, SI, IN_HALF>(h, i0, r0);
                load_row2<CI, SI, IN_HALF>(h, i1, r1);
                load_row2<CI, SI, IN_HALF>(h, i2, r2);
                load_row2<CI, SI, IN_HALF>(h, i3, r3);
#pragma unroll
                for (int c = 0; c < CI; c++) acc[c] += (r0[c] + r1[c]) + (r2[c] + r3[c]);
            }
        }
        // 2 rows in flight
        for (; j + G < end; j += 2 * G) {
            int i0 = col[j], i1 = col[j + G];
            float r0[CI], r1[CI];
            load_row2<CI, SI, IN_HALF>(h, i0, r0);
            load_row2<CI, SI, IN_HALF>(h, i1, r1);
#pragma unroll
            for (int c = 0; c < CI; c++) acc[c] += r0[c] + r1[c];
        }
        if (j < end) {
            float r0[CI];
            load_row2<CI, SI, IN_HALF>(h, col[j], r0);
#pragma unroll
            for (int c = 0; c < CI; c++) acc[c] += r0[c];
        }
    }

    // butterfly: all G lanes end with the full neighbor sum
#pragma unroll
    for (int m = 1; m < G; m <<= 1)
#pragma unroll
        for (int c = 0; c < CI; c++) acc[c] += __shfl_xor(acc[c], m);

    float out[OPL];
    float nrm2 = 0.0f;
    if (valid) {
        float ic = 1.0f / fmaxf((float)(end - beg), 1.0f);
        float xin[CI];
        load_row2<CI, SI, IN_HALF>(h, node, xin);
        float agg[CI];
#pragma unroll
        for (int c = 0; c < CI; c++) {
            float a  = acc[c] * ic;
            float xv = xin[c];
            if (IN_AFFINE) {
                a  = a  * sSc[c] + sSh[c];
                xv = xv * sSc[c] + sSh[c];
            }
            agg[c] = a;
            xin[c] = xv;
        }
#pragma unroll
        for (int k = 0; k < OPL; k++) {
            int o = g * OPL + k;
            float v = 0.0f;
            if (o < CO) {
                v = sBl[o];
#pragma unroll
                for (int c = 0; c < CI; c++)
                    v += sWl[o * PCI + c] * agg[c] + sWr[o * PCI + c] * xin[c];
            }
            out[k] = v;
            nrm2 += v * v;
        }
    }
#pragma unroll
    for (int m = 1; m < G; m <<= 1) nrm2 += __shfl_xor(nrm2, m);

    if (valid) {
        float inv_nrm = 1.0f / fmaxf(sqrtf(nrm2), L2_EPS);
#pragma unroll
        for (int k = 0; k < OPL; k++) {
            int o = g * OPL + k;
            float v = (o < CO) ? fmaxf(out[k] * inv_nrm, 0.0f) : 0.0f;  // L2 norm + ReLU
            if constexpr (OUT_HALF) {
                if (o < SO) ((__half*)y)[(long)node * SO + o] = __float2half_rn(v);  // pad -> 0
            } else {
                if (o < CO) ((float*)y)[(long)node * SO + o] = v;
            }
            if (DO_STATS && o < CO) {
                atomicAdd(&red_sum[o], v);
                atomicAdd(&red_sq[o], v * v);
            }
        }
    }

    if (DO_STATS) {
        __syncthreads();
        if (threadIdx.x < CO) {
            int slot = blockIdx.x & (NSLOT - 1);
            atomicAdd(&stat_sum[slot * 64 + threadIdx.x], red_sum[threadIdx.x]);
            atomicAdd(&stat_sq [slot * 64 + threadIdx.x], red_sq[threadIdx.x]);
        }
    }
}

// ---------------------------------------------------------------------------
extern "C" void kernel_launch(void* const* d_in, const int* in_sizes, int n_in,
                              void* d_out, int out_size, void* d_ws, size_t ws_size,
                              hipStream_t stream) {
    const float* x   = (const float*)d_in[0];
    const int*   ei  = (const int*)d_in[1];
    const int*   src = ei;
    const int*   dst = ei + NEDGES;

    const float* w1l = (const float*)d_in[2];
    const float* b1l = (const float*)d_in[3];
    const float* w1r = (const float*)d_in[4];
    const float* w2l = (const float*)d_in[5];
    const float* b2l = (const float*)d_in[6];
    const float* w2r = (const float*)d_in[7];
    const float* w3l = (const float*)d_in[8];
    const float* b3l = (const float*)d_in[9];
    const float* w3r = (const float*)d_in[10];
    const float* w4l = (const float*)d_in[11];
    const float* b4l = (const float*)d_in[12];
    const float* w4r = (const float*)d_in[13];
    const float* g1  = (const float*)d_in[14];
    const float* be1 = (const float*)d_in[15];
    const float* g2  = (const float*)d_in[16];
    const float* be2 = (const float*)d_in[17];
    const float* g3  = (const float*)d_in[18];
    const float* be3 = (const float*)d_in[19];

    char* w = (char*)d_ws;
    int* blk_hist     = (int*)w;  w += NBLK_E * NBKT * 4;
    int* blk_off      = (int*)w;  w += NBLK_E * NBKT * 4;
    int* bucket_total = (int*)w;  w += 256 * 4;
    int* row_ptr      = (int*)w;  w += (NNODES + 8) * 4;
    int* col          = (int*)w;  w += NEDGES * 4;
    __half* hA        = (__half*)w; w += NNODES * 16 * 4;  // fp16 tables (slab over-alloc)
    __half* hB        = (__half*)w; w += NNODES * 16 * 4;  // aliased by staged
    float* stats      = (float*)w; w += 3 * NSLOT * 64 * 4;
    unsigned int* staged = (unsigned int*)hB;  // dead before hB is written

    float* ssum1 = stats + 0 * NSLOT * 64, *ssq1 = ssum1 + 32;
    float* ssum2 = stats + 1 * NSLOT * 64, *ssq2 = ssum2 + 32;
    float* ssum3 = stats + 2 * NSLOT * 64, *ssq3 = ssum3 + 32;

    // atomic-free CSR build (LDS atomics only), 4 launches — round-2 proven
    hist_kernel   <<<NBLK_E, 512, 0, stream>>>(dst, blk_hist, stats);
    scan_blocks   <<<NBKT, 256, 0, stream>>>(blk_hist, blk_off, bucket_total);
    bucket_scatter<<<NBLK_E, 512, 0, stream>>>(src, dst, blk_off, bucket_total, staged);
    csr_finalize  <<<NBKT, 512, 0, stream>>>(staged, bucket_total, row_ptr, col);

    const int NLB = (NNODES * 8 + 255) / 256;   // 3125 blocks (G=8)

    // layer 1: 4 -> 6; in fp32 x (SI=4), out fp16 hA (SO=8 halves), +stats
    layer_kernel<4, 4, 6, 8, 8, false, true, false, true><<<NLB, 256, 0, stream>>>(
        row_ptr, col, x, nullptr, nullptr, nullptr, nullptr,
        w1l, b1l, w1r, hA, ssum1, ssq1);

    // layer 2: 6 -> 8; in fp16 hA (SI=8, 1 load/row), BN1 in-block, out fp16 hB, +stats
    layer_kernel<6, 8, 8, 8, 8, true, true, true, true><<<NLB, 256, 0, stream>>>(
        row_ptr, col, hA, ssum1, ssq1, g1, be1,
        w2l, b2l, w2r, hB, ssum2, ssq2);

    // layer 3: 8 -> 16; in fp16 hB (SI=8, 1 load/row), BN2, out fp16 hA, +stats
    layer_kernel<8, 8, 16, 16, 8, true, true, true, true><<<NLB, 256, 0, stream>>>(
        row_ptr, col, hB, ssum2, ssq2, g2, be2,
        w3l, b3l, w3r, hA, ssum3, ssq3);

    // layer 4: 16 -> 32; in fp16 hA (SI=16, 2 loads/row), BN3, ReLU -> fp32 d_out
    layer_kernel<16, 16, 32, 32, 8, true, false, true, false><<<NLB, 256, 0, stream>>>(
        row_ptr, col, hA, ssum3, ssq3, g3, be3,
        w4l, b4l, w4r, d_out, nullptr, nullptr);
}